// Round 2
// baseline (3442.229 us; speedup 1.0000x reference)
//
#include <hip/hip_runtime.h>

typedef short bf16x8 __attribute__((ext_vector_type(8)));
typedef float f32x4 __attribute__((ext_vector_type(4)));
typedef unsigned short u16;
typedef unsigned int u32;
typedef unsigned long long u64;

#define NPTS 16384
#define NPOINT 1024
#define STOT 524288   // 16*1024*32 samples

__device__ __forceinline__ u16 f2bf(float f){
  u32 u = __builtin_bit_cast(u32, f);
  u += 0x7fffu + ((u >> 16) & 1u);
  return (u16)(u >> 16);
}
__device__ __forceinline__ float bf2f(u16 u){
  u32 x = ((u32)u) << 16;
  return __builtin_bit_cast(float, x);
}

// ---------------------------------------------------------------- FPS
// one block per batch; 1024 threads, 16 points/thread in registers.
// argmax reduce: pack (dist,~idx) into u64, 2 DPP quad levels, LDS atomicMax
// into ping-pong slot -> 2 barriers/iter, no dependent bpermute chain.
__global__ __launch_bounds__(1024) void fps_kernel(const float* __restrict__ xyz,
                                                   const int* __restrict__ finit,
                                                   float* __restrict__ out0){
  __shared__ float cx, cy, cz;
  __shared__ u64 slot[2];
  const int b = blockIdx.x, t = threadIdx.x;
  const float* xb = xyz + (size_t)b * 3 * NPTS;
  float px[16], py[16], pz[16], dist[16];
#pragma unroll
  for (int k = 0; k < 16; k++){
    int n = (k << 10) + t;
    px[k] = xb[n];
    py[k] = xb[NPTS + n];
    pz[k] = xb[2*NPTS + n];
    dist[k] = 1e10f;
  }
  if (t < 2) slot[t] = 0ULL;
  const int far0 = finit[b];
  if (t == (far0 & 1023)){
    int kk = far0 >> 10;
    float sx = px[0], sy = py[0], sz = pz[0];
#pragma unroll
    for (int k = 1; k < 16; k++){
      bool e = (kk == k);
      sx = e ? px[k] : sx; sy = e ? py[k] : sy; sz = e ? pz[k] : sz;
    }
    cx = sx; cy = sy; cz = sz;
  }
  __syncthreads();
  for (int it = 0; it < NPOINT; it++){
    float ccx = cx, ccy = cy, ccz = cz;
    if (t < 3) out0[((size_t)b*3 + t)*NPOINT + it] = (t==0) ? ccx : ((t==1) ? ccy : ccz);
    float bv = -1.f; int bk = 0;
#pragma unroll
    for (int k = 0; k < 16; k++){
      // mimic plain f32 evaluation (no fma contraction) to match the reference argmax
      float dx = __fsub_rn(px[k], ccx);
      float dy = __fsub_rn(py[k], ccy);
      float dz = __fsub_rn(pz[k], ccz);
      float dd = __fadd_rn(__fadd_rn(__fmul_rn(dx,dx), __fmul_rn(dy,dy)), __fmul_rn(dz,dz));
      float dm = fminf(dist[k], dd);
      dist[k] = dm;
      bool g = dm > bv;
      bv = g ? dm : bv;
      bk = g ? k : bk;
    }
    // bv >= 0 after the k-loop, so uint order on the float bits == float order.
    int bi = (bk << 10) + t;   // global point index; ties -> smaller index wins via ~bi
    u64 key = ((u64)__builtin_bit_cast(u32, bv) << 32) | (u32)(~(u32)bi);
    // quad reduce via DPP (cheap VALU, no DS traffic)
    {
      u32 lo = (u32)key, hi = (u32)(key >> 32);
      u32 lo1 = (u32)__builtin_amdgcn_update_dpp(0, (int)lo, 0xB1, 0xf, 0xf, true); // quad_perm [1,0,3,2]
      u32 hi1 = (u32)__builtin_amdgcn_update_dpp(0, (int)hi, 0xB1, 0xf, 0xf, true);
      u64 k1 = ((u64)hi1 << 32) | lo1;
      if (k1 > key) key = k1;
      lo = (u32)key; hi = (u32)(key >> 32);
      lo1 = (u32)__builtin_amdgcn_update_dpp(0, (int)lo, 0x4E, 0xf, 0xf, true);     // quad_perm [2,3,0,1]
      hi1 = (u32)__builtin_amdgcn_update_dpp(0, (int)hi, 0x4E, 0xf, 0xf, true);
      k1 = ((u64)hi1 << 32) | lo1;
      if (k1 > key) key = k1;
    }
    if ((t & 3) == 0) atomicMax(&slot[it & 1], key);
    __syncthreads();
    u64 win = slot[it & 1];
    int nb = (int)(~(u32)win);
    if (t == 0) slot[(it & 1) ^ 1] = 0ULL;   // reset the other slot for next iter
    if (t == (nb & 1023)){
      int kk = nb >> 10;
      float sx = px[0], sy = py[0], sz = pz[0];
#pragma unroll
      for (int k = 1; k < 16; k++){
        bool e = (kk == k);
        sx = e ? px[k] : sx; sy = e ? py[k] : sy; sz = e ? pz[k] : sz;
      }
      cx = sx; cy = sy; cz = sz;
    }
    __syncthreads();
  }
}

// ---------------------------------------------------------------- pack XP[b][n][96] bf16 (xyz || points, zero pad)
__global__ __launch_bounds__(256) void pack_kernel(const float* __restrict__ xyz,
                                                   const float* __restrict__ points,
                                                   u16* __restrict__ XP){
  __shared__ float ldsb[67*256];
  const int blk = blockIdx.x, t = threadIdx.x;
  const int b = blk >> 6;
  const int n0 = (blk & 63) << 8;
  for (int c = 0; c < 67; c++){
    const float* src = (c < 3) ? (xyz + ((size_t)b*3 + c)*NPTS)
                               : (points + ((size_t)b*64 + (c-3))*NPTS);
    ldsb[c*256 + t] = src[n0 + t];
  }
  __syncthreads();
  u16* dst = XP + ((size_t)b*NPTS + n0)*96;
  for (int itc = 0; itc < 12; itc++){
    int q = t + (itc << 8);          // 3072 16B-chunks, consecutive => coalesced
    int r = q / 12, ch = q % 12;
    u16 tmp[8];
#pragma unroll
    for (int j = 0; j < 8; j++){
      int c = ch*8 + j;
      tmp[j] = (c < 67) ? f2bf(ldsb[c*256 + r]) : (u16)0;
    }
    uint4 v;
    v.x = (u32)tmp[0] | ((u32)tmp[1] << 16);
    v.y = (u32)tmp[2] | ((u32)tmp[3] << 16);
    v.z = (u32)tmp[4] | ((u32)tmp[5] << 16);
    v.w = (u32)tmp[6] | ((u32)tmp[7] << 16);
    *(uint4*)(dst + q*8) = v;
  }
}

// ---------------------------------------------------------------- small prep: zero stat buckets + pack weights bf16
__global__ __launch_bounds__(256) void prep_small(const float* __restrict__ W0,
                                                  const float* __restrict__ W1,
                                                  const float* __restrict__ W2,
                                                  u16* __restrict__ W0bf,
                                                  u16* __restrict__ W1bf,
                                                  u16* __restrict__ W2bf,
                                                  float* __restrict__ statsF){
  const int blk = blockIdx.x, t = threadIdx.x;
  if (blk < 48){
#pragma unroll
    for (int k = 0; k < 4; k++) statsF[blk*1024 + k*256 + t] = 0.f;
  } else if (blk == 48){
    for (int i = t; i < 64*96; i += 256){
      int n = i / 96, k = i % 96;
      W0bf[i] = (k < 67) ? f2bf(W0[n*67 + k]) : (u16)0;
    }
  } else if (blk <= 50){
    for (int i = (blk-49)*256 + t; i < 128*64; i += 512) W1bf[i] = f2bf(W1[i]);
  } else if (blk <= 54){
    for (int i = (blk-51)*256 + t; i < 128*128; i += 1024) W2bf[i] = f2bf(W2[i]);
  }
}

// ---------------------------------------------------------------- layer 0: gather + matmul (K=96 padded), stats
__global__ __launch_bounds__(256) void l0_kernel(const u16* __restrict__ XP,
                                                 const int* __restrict__ gidx,
                                                 const u16* __restrict__ W0bf,
                                                 u16* __restrict__ y0,
                                                 float* __restrict__ bsum, float* __restrict__ bsqr){
  __shared__ float lsum[64], lsqr[64];
  const int blk = blockIdx.x, t = threadIdx.x;
  const int b = blk >> 8, j = blk & 255;
  const int wave = t >> 6, lane = t & 63, lrow = lane & 15, lq = lane >> 4;
  if (t < 64){ lsum[t] = 0.f; lsqr[t] = 0.f; }
  __syncthreads();
  const size_t srow = (size_t)blk * 128;
  const int m0 = wave*32 + lrow, m1 = m0 + 16;
  const int gbase = b*32768 + j*128;
  const int p0 = gidx[gbase + m0];
  const int p1 = gidx[gbase + m1];
  const bf16x8* ar0 = (const bf16x8*)(XP + ((size_t)b*NPTS + p0)*96);
  const bf16x8* ar1 = (const bf16x8*)(XP + ((size_t)b*NPTS + p1)*96);
  f32x4 acc[2][4];
#pragma unroll
  for (int mt = 0; mt < 2; mt++)
#pragma unroll
    for (int nt = 0; nt < 4; nt++){ f32x4 z = {0.f,0.f,0.f,0.f}; acc[mt][nt] = z; }
#pragma unroll
  for (int ks = 0; ks < 3; ks++){
    bf16x8 af0 = ar0[ks*4 + lq];
    bf16x8 af1 = ar1[ks*4 + lq];
#pragma unroll
    for (int nt = 0; nt < 4; nt++){
      bf16x8 bb = *(const bf16x8*)(W0bf + (nt*16 + lrow)*96 + ks*32 + lq*8);
      acc[0][nt] = __builtin_amdgcn_mfma_f32_16x16x32_bf16(af0, bb, acc[0][nt], 0, 0, 0);
      acc[1][nt] = __builtin_amdgcn_mfma_f32_16x16x32_bf16(af1, bb, acc[1][nt], 0, 0, 0);
    }
  }
#pragma unroll
  for (int nt = 0; nt < 4; nt++){
    float s = 0.f, s2 = 0.f;
#pragma unroll
    for (int mt = 0; mt < 2; mt++){
#pragma unroll
      for (int i = 0; i < 4; i++){
        float u = acc[mt][nt][i];
        s += u; s2 = fmaf(u, u, s2);
        int m = wave*32 + mt*16 + lq*4 + i;
        y0[(srow + m)*64 + nt*16 + lrow] = f2bf(u);
      }
    }
    s  += __shfl_xor(s, 16, 64);  s  += __shfl_xor(s, 32, 64);
    s2 += __shfl_xor(s2, 16, 64); s2 += __shfl_xor(s2, 32, 64);
    if (lane < 16){ atomicAdd(&lsum[nt*16 + lane], s); atomicAdd(&lsqr[nt*16 + lane], s2); }
  }
  __syncthreads();
  if (t < 64){
    int bkt = blk & 63;
    atomicAdd(&bsum[bkt*128 + t], lsum[t]);
    atomicAdd(&bsqr[bkt*128 + t], lsqr[t]);
  }
}

// ---------------------------------------------------------------- stats finalize: a = g*rsqrt(var+eps), d = be - mean*a
__global__ __launch_bounds__(128) void stats_kernel(const float* __restrict__ bsum,
                                                    const float* __restrict__ bsqr,
                                                    const float* __restrict__ g,
                                                    const float* __restrict__ be,
                                                    float* __restrict__ a, float* __restrict__ d, int C){
  const int c = threadIdx.x;
  if (c >= C) return;
  float s = 0.f, s2 = 0.f;
  for (int k = 0; k < 64; k++){ s += bsum[k*128 + c]; s2 += bsqr[k*128 + c]; }
  const float inv = 1.f / (float)STOT;
  float m = s * inv;
  float v = s2 * inv - m*m;
  float aa = g[c] / sqrtf(v + 1e-5f);
  a[c] = aa;
  d[c] = be[c] - m*aa;
}

__device__ __forceinline__ bf16x8 load_bn_relu(const u16* __restrict__ row, int ko,
                                               const float* __restrict__ av,
                                               const float* __restrict__ dv){
  uint4 r = *(const uint4*)(row + ko);
  u32 w[4] = {r.x, r.y, r.z, r.w};
  bf16x8 out;
#pragma unroll
  for (int jj = 0; jj < 8; jj++){
    u16 us = (u16)(w[jj >> 1] >> ((jj & 1) * 16));
    float h = fmaxf(fmaf(av[ko + jj], bf2f(us), dv[ko + jj]), 0.f);
    out[jj] = (short)f2bf(h);
  }
  return out;
}

// ---------------------------------------------------------------- layer 1: K=64 -> Cout=128
__global__ __launch_bounds__(256) void l1_kernel(const u16* __restrict__ y0,
                                                 const u16* __restrict__ W1bf,
                                                 const float* __restrict__ a0, const float* __restrict__ d0,
                                                 u16* __restrict__ y1,
                                                 float* __restrict__ bsum, float* __restrict__ bsqr){
  __shared__ float lsum[128], lsqr[128];
  __shared__ float av[64], dv[64];
  const int blk = blockIdx.x, t = threadIdx.x;
  const int wave = t >> 6, lane = t & 63, lrow = lane & 15, lq = lane >> 4;
  if (t < 128){ lsum[t] = 0.f; lsqr[t] = 0.f; }
  if (t < 64){ av[t] = a0[t]; dv[t] = d0[t]; }
  __syncthreads();
  const size_t srow = (size_t)blk * 128;
  const int m0 = wave*32 + lrow, m1 = m0 + 16;
  const u16* row0 = y0 + (srow + m0)*64;
  const u16* row1 = y0 + (srow + m1)*64;
  f32x4 acc[2][8];
#pragma unroll
  for (int mt = 0; mt < 2; mt++)
#pragma unroll
    for (int nt = 0; nt < 8; nt++){ f32x4 z = {0.f,0.f,0.f,0.f}; acc[mt][nt] = z; }
#pragma unroll
  for (int ks = 0; ks < 2; ks++){
    const int ko = ks*32 + lq*8;
    bf16x8 af0 = load_bn_relu(row0, ko, av, dv);
    bf16x8 af1 = load_bn_relu(row1, ko, av, dv);
#pragma unroll
    for (int nt = 0; nt < 8; nt++){
      bf16x8 bb = *(const bf16x8*)(W1bf + (nt*16 + lrow)*64 + ko);
      acc[0][nt] = __builtin_amdgcn_mfma_f32_16x16x32_bf16(af0, bb, acc[0][nt], 0, 0, 0);
      acc[1][nt] = __builtin_amdgcn_mfma_f32_16x16x32_bf16(af1, bb, acc[1][nt], 0, 0, 0);
    }
  }
#pragma unroll
  for (int nt = 0; nt < 8; nt++){
    float s = 0.f, s2 = 0.f;
#pragma unroll
    for (int mt = 0; mt < 2; mt++){
#pragma unroll
      for (int i = 0; i < 4; i++){
        float u = acc[mt][nt][i];
        s += u; s2 = fmaf(u, u, s2);
        int m = wave*32 + mt*16 + lq*4 + i;
        y1[(srow + m)*128 + nt*16 + lrow] = f2bf(u);
      }
    }
    s  += __shfl_xor(s, 16, 64);  s  += __shfl_xor(s, 32, 64);
    s2 += __shfl_xor(s2, 16, 64); s2 += __shfl_xor(s2, 32, 64);
    if (lane < 16){ atomicAdd(&lsum[nt*16 + lane], s); atomicAdd(&lsqr[nt*16 + lane], s2); }
  }
  __syncthreads();
  if (t < 128){
    int bkt = blk & 63;
    atomicAdd(&bsum[bkt*128 + t], lsum[t]);
    atomicAdd(&bsqr[bkt*128 + t], lsqr[t]);
  }
}

// ---------------------------------------------------------------- layer 2: K=128 -> Cout=128; emit per-group max/min of pre-BN y2
__global__ __launch_bounds__(256) void l2_kernel(const u16* __restrict__ y1,
                                                 const u16* __restrict__ W2bf,
                                                 const float* __restrict__ a1, const float* __restrict__ d1,
                                                 float* __restrict__ maxb, float* __restrict__ minb,
                                                 float* __restrict__ bsum, float* __restrict__ bsqr){
  __shared__ float lsum[128], lsqr[128];
  __shared__ float av[128], dv[128];
  const int blk = blockIdx.x, t = threadIdx.x;
  const int wave = t >> 6, lane = t & 63, lrow = lane & 15, lq = lane >> 4;
  if (t < 128){ lsum[t] = 0.f; lsqr[t] = 0.f; av[t] = a1[t]; dv[t] = d1[t]; }
  __syncthreads();
  const size_t srow = (size_t)blk * 128;
  const int m0 = wave*32 + lrow, m1 = m0 + 16;
  const u16* row0 = y1 + (srow + m0)*128;
  const u16* row1 = y1 + (srow + m1)*128;
  f32x4 acc[2][8];
#pragma unroll
  for (int mt = 0; mt < 2; mt++)
#pragma unroll
    for (int nt = 0; nt < 8; nt++){ f32x4 z = {0.f,0.f,0.f,0.f}; acc[mt][nt] = z; }
#pragma unroll
  for (int ks = 0; ks < 4; ks++){
    const int ko = ks*32 + lq*8;
    bf16x8 af0 = load_bn_relu(row0, ko, av, dv);
    bf16x8 af1 = load_bn_relu(row1, ko, av, dv);
#pragma unroll
    for (int nt = 0; nt < 8; nt++){
      bf16x8 bb = *(const bf16x8*)(W2bf + (nt*16 + lrow)*128 + ko);
      acc[0][nt] = __builtin_amdgcn_mfma_f32_16x16x32_bf16(af0, bb, acc[0][nt], 0, 0, 0);
      acc[1][nt] = __builtin_amdgcn_mfma_f32_16x16x32_bf16(af1, bb, acc[1][nt], 0, 0, 0);
    }
  }
#pragma unroll
  for (int nt = 0; nt < 8; nt++){
    float s = 0.f, s2 = 0.f, mx = -3.4e38f, mn = 3.4e38f;
#pragma unroll
    for (int mt = 0; mt < 2; mt++){
#pragma unroll
      for (int i = 0; i < 4; i++){
        float u = acc[mt][nt][i];
        s += u; s2 = fmaf(u, u, s2);
        mx = fmaxf(mx, u); mn = fminf(mn, u);
      }
    }
    s  += __shfl_xor(s, 16, 64);  s  += __shfl_xor(s, 32, 64);
    s2 += __shfl_xor(s2, 16, 64); s2 += __shfl_xor(s2, 32, 64);
    mx = fmaxf(mx, __shfl_xor(mx, 16, 64)); mx = fmaxf(mx, __shfl_xor(mx, 32, 64));
    mn = fminf(mn, __shfl_xor(mn, 16, 64)); mn = fminf(mn, __shfl_xor(mn, 32, 64));
    if (lane < 16){
      size_t gi = ((size_t)blk*4 + wave)*128 + nt*16 + lane;
      maxb[gi] = mx; minb[gi] = mn;
      atomicAdd(&lsum[nt*16 + lane], s); atomicAdd(&lsqr[nt*16 + lane], s2);
    }
  }
  __syncthreads();
  if (t < 128){
    int bkt = blk & 63;
    atomicAdd(&bsum[bkt*128 + t], lsum[t]);
    atomicAdd(&bsqr[bkt*128 + t], lsqr[t]);
  }
}

// ---------------------------------------------------------------- final: BN2+relu on group max/min, transpose-store [B,128,NP]
__global__ __launch_bounds__(256) void final_kernel(const float* __restrict__ maxb,
                                                    const float* __restrict__ minb,
                                                    const float* __restrict__ a2, const float* __restrict__ d2,
                                                    float* __restrict__ out1){
  __shared__ float ldsb[64*129];
  __shared__ float av[128], dv[128];
  const int blk = blockIdx.x, t = threadIdx.x;
  const int b = blk >> 4, np0 = (blk & 15) << 6;
  if (t < 128){ av[t] = a2[t]; dv[t] = d2[t]; }
  __syncthreads();
  const size_t base = ((size_t)b*NPOINT + np0)*128;
  for (int itc = 0; itc < 32; itc++){
    int e = t + (itc << 8);
    int npl = e >> 7, c = e & 127;
    float a = av[c];
    float mxv = maxb[base + e], mnv = minb[base + e];
    float vsel = (a >= 0.f) ? mxv : mnv;
    ldsb[npl*129 + c] = fmaxf(fmaf(a, vsel, dv[c]), 0.f);
  }
  __syncthreads();
  for (int itc = 0; itc < 32; itc++){
    int e = t + (itc << 8);
    int c = e >> 6, npl = e & 63;
    out1[((size_t)b*128 + c)*NPOINT + np0 + npl] = ldsb[npl*129 + c];
  }
}

// ---------------------------------------------------------------- launch
extern "C" void kernel_launch(void* const* d_in, const int* in_sizes, int n_in,
                              void* d_out, int out_size, void* d_ws, size_t ws_size,
                              hipStream_t stream) {
  const float* xyz    = (const float*)d_in[0];
  const float* points = (const float*)d_in[1];
  const int*   finit  = (const int*)d_in[2];
  const int*   gidx   = (const int*)d_in[3];
  const float* W0  = (const float*)d_in[4];
  const float* g0v = (const float*)d_in[6];
  const float* be0 = (const float*)d_in[7];
  const float* W1  = (const float*)d_in[8];
  const float* g1v = (const float*)d_in[10];
  const float* be1 = (const float*)d_in[11];
  const float* W2  = (const float*)d_in[12];
  const float* g2v = (const float*)d_in[14];
  const float* be2 = (const float*)d_in[15];

  float* out0 = (float*)d_out;
  float* out1 = out0 + 16*3*NPOINT;   // 49152

  char* ws = (char*)d_ws;
  u16* XP = (u16*)ws;                               // 48 MiB, dead after l0
  u16* y1 = (u16*)ws;                               // 128 MiB (aliases XP; written in l1)
  u16* y0 = (u16*)(ws + 134217728);                 // 64 MiB
  float* maxb = (float*)(ws + 134217728);           // aliases y0 (dead after l1)
  float* minb = (float*)(ws + 134217728 + 8388608);
  float* statsF = (float*)(ws + 201326592);
  float* bsum0 = statsF;          float* bsqr0 = statsF + 8192;
  float* bsum1 = statsF + 16384;  float* bsqr1 = statsF + 24576;
  float* bsum2 = statsF + 32768;  float* bsqr2 = statsF + 40960;
  float* a0 = statsF + 49152;       float* d0 = a0 + 128;
  float* a1 = statsF + 49152 + 256; float* d1 = a1 + 128;
  float* a2 = statsF + 49152 + 512; float* d2 = a2 + 128;
  u16* W0bf = (u16*)(statsF + 49920);
  u16* W1bf = W0bf + 64*96;
  u16* W2bf = W1bf + 128*64;

  fps_kernel<<<16, 1024, 0, stream>>>(xyz, finit, out0);
  prep_small<<<64, 256, 0, stream>>>(W0, W1, W2, W0bf, W1bf, W2bf, statsF);
  pack_kernel<<<1024, 256, 0, stream>>>(xyz, points, XP);
  l0_kernel<<<4096, 256, 0, stream>>>(XP, gidx, W0bf, y0, bsum0, bsqr0);
  stats_kernel<<<1, 128, 0, stream>>>(bsum0, bsqr0, g0v, be0, a0, d0, 64);
  l1_kernel<<<4096, 256, 0, stream>>>(y0, W1bf, a0, d0, y1, bsum1, bsqr1);
  stats_kernel<<<1, 128, 0, stream>>>(bsum1, bsqr1, g1v, be1, a1, d1, 128);
  l2_kernel<<<4096, 256, 0, stream>>>(y1, W2bf, a1, d1, maxb, minb, bsum2, bsqr2);
  stats_kernel<<<1, 128, 0, stream>>>(bsum2, bsqr2, g2v, be2, a2, d2, 128);
  final_kernel<<<256, 256, 0, stream>>>(maxb, minb, a2, d2, out1);
}

// Round 3
// 2231.125 us; speedup vs baseline: 1.5428x; 1.5428x over previous
//
#include <hip/hip_runtime.h>

typedef short bf16x8 __attribute__((ext_vector_type(8)));
typedef float f32x4 __attribute__((ext_vector_type(4)));
typedef float f32x2 __attribute__((ext_vector_type(2)));
typedef unsigned short u16;
typedef unsigned int u32;
typedef unsigned long long u64;

#define NPTS 16384
#define NPOINT 1024
#define STOT 524288   // 16*1024*32 samples

__device__ __forceinline__ u16 f2bf(float f){
  u32 u = __builtin_bit_cast(u32, f);
  u += 0x7fffu + ((u >> 16) & 1u);
  return (u16)(u >> 16);
}
__device__ __forceinline__ float bf2f(u16 u){
  u32 x = ((u32)u) << 16;
  return __builtin_bit_cast(float, x);
}

// 64-bit max-combine across lanes via DPP (pure VALU, no DS pipe).
template<int CTRL>
__device__ __forceinline__ u64 dpp_max(u64 key){
  u32 lo = (u32)key, hi = (u32)(key >> 32);
  u32 lo1 = (u32)__builtin_amdgcn_update_dpp(0, (int)lo, CTRL, 0xf, 0xf, true);
  u32 hi1 = (u32)__builtin_amdgcn_update_dpp(0, (int)hi, CTRL, 0xf, 0xf, true);
  u64 k1 = ((u64)hi1 << 32) | (u64)lo1;
  return (k1 > key) ? k1 : key;
}

// ---------------------------------------------------------------- FPS
// one block per batch; 1024 threads, 16 points/thread in registers (packed f32x2).
// reduce: u64 key (dist_bits<<32 | ~idx); full-wave DPP max (quad_perm x2,
// half_mirror, mirror, bcast15, bcast31) -> lane63 writes 1 u64/wave to LDS;
// ONE barrier; stage2 = indexed ds_read_b64 + 4 DPP levels (all lanes agree).
// Center coords fetched from a float4-interleaved global copy (uniform scalar
// load) -> no owner-write barrier.
__global__ __launch_bounds__(1024) void fps_kernel(const float* __restrict__ xyz,
                                                   const int* __restrict__ finit,
                                                   float4* __restrict__ xpk_all,
                                                   float* __restrict__ out0){
  __shared__ u64 warr[2][16];
  const int b = blockIdx.x, t = threadIdx.x;
  const int wave = t >> 6, lane = t & 63;
  const float* xb = xyz + (size_t)b * 3 * NPTS;
  float4* xpk = xpk_all + (size_t)b * NPTS;
  f32x2 px[8], py[8], pz[8], dist[8];
#pragma unroll
  for (int j = 0; j < 8; j++){
    f32x2 x, y, z;
#pragma unroll
    for (int h = 0; h < 2; h++){
      int n = ((2*j + h) << 10) + t;
      x[h] = xb[n];
      y[h] = xb[NPTS + n];
      z[h] = xb[2*NPTS + n];
      xpk[n] = make_float4(x[h], y[h], z[h], 0.f);
    }
    px[j] = x; py[j] = y; pz[j] = z;
    f32x2 big = {1e10f, 1e10f};
    dist[j] = big;
  }
  if (t < 32) ((u64*)warr)[t] = 0ULL;
  const int far0 = finit[b];          // uniform
  __syncthreads();                    // xpk + warr visible block-wide
  int nbu = far0;
  for (int it = 0; it < NPOINT; it++){
    float4 cc = xpk[nbu];             // uniform index -> scalar/broadcast load
    if (t == 0){
      out0[((size_t)b*3 + 0)*NPOINT + it] = cc.x;
      out0[((size_t)b*3 + 1)*NPOINT + it] = cc.y;
      out0[((size_t)b*3 + 2)*NPOINT + it] = cc.z;
    }
    float bv = -1.f; int bk = 0;
    {
#pragma clang fp contract(off)
      f32x2 cx2 = {cc.x, cc.x}, cy2 = {cc.y, cc.y}, cz2 = {cc.z, cc.z};
#pragma unroll
      for (int j = 0; j < 8; j++){
        f32x2 dx = px[j] - cx2;
        f32x2 dy = py[j] - cy2;
        f32x2 dz = pz[j] - cz2;
        f32x2 dd = dx*dx + dy*dy + dz*dz;   // contract off: pk_mul x3 + pk_add x2
        f32x2 dm = __builtin_elementwise_min(dist[j], dd);
        dist[j] = dm;
        // ascending k order keeps smallest index among in-thread ties
        bool g0 = dm.x > bv;
        bv = g0 ? dm.x : bv;  bk = g0 ? (2*j)   : bk;
        bool g1 = dm.y > bv;
        bv = g1 ? dm.y : bv;  bk = g1 ? (2*j+1) : bk;
      }
    }
    // bv >= 0, so uint order on float bits == float order; ~idx: ties -> smaller idx
    int bi = (bk << 10) + t;
    u64 key = ((u64)__builtin_bit_cast(u32, bv) << 32) | (u64)(u32)(~(u32)bi);
    key = dpp_max<0xB1>(key);   // quad_perm [1,0,3,2]  (xor 1)
    key = dpp_max<0x4E>(key);   // quad_perm [2,3,0,1]  (xor 2)
    key = dpp_max<0x141>(key);  // row_half_mirror      (== xor 4 here)
    key = dpp_max<0x140>(key);  // row_mirror           (== xor 8 here)
    key = dpp_max<0x142>(key);  // row_bcast15
    key = dpp_max<0x143>(key);  // row_bcast31 -> lane 63 has wave max
    if (lane == 63) warr[it & 1][wave] = key;
    __syncthreads();
    u64 kv = warr[it & 1][lane & 15];
    kv = dpp_max<0xB1>(kv);
    kv = dpp_max<0x4E>(kv);
    kv = dpp_max<0x141>(kv);
    kv = dpp_max<0x140>(kv);    // every lane: max of the 16 wave keys
    int nb = (int)(~(u32)kv);
    nbu = __builtin_amdgcn_readfirstlane(nb);
  }
}

// ---------------------------------------------------------------- pack XP[b][n][96] bf16 (xyz || points, zero pad)
__global__ __launch_bounds__(256) void pack_kernel(const float* __restrict__ xyz,
                                                   const float* __restrict__ points,
                                                   u16* __restrict__ XP){
  __shared__ float ldsb[67*256];
  const int blk = blockIdx.x, t = threadIdx.x;
  const int b = blk >> 6;
  const int n0 = (blk & 63) << 8;
  for (int c = 0; c < 67; c++){
    const float* src = (c < 3) ? (xyz + ((size_t)b*3 + c)*NPTS)
                               : (points + ((size_t)b*64 + (c-3))*NPTS);
    ldsb[c*256 + t] = src[n0 + t];
  }
  __syncthreads();
  u16* dst = XP + ((size_t)b*NPTS + n0)*96;
  for (int itc = 0; itc < 12; itc++){
    int q = t + (itc << 8);          // 3072 16B-chunks, consecutive => coalesced
    int r = q / 12, ch = q % 12;
    u16 tmp[8];
#pragma unroll
    for (int j = 0; j < 8; j++){
      int c = ch*8 + j;
      tmp[j] = (c < 67) ? f2bf(ldsb[c*256 + r]) : (u16)0;
    }
    uint4 v;
    v.x = (u32)tmp[0] | ((u32)tmp[1] << 16);
    v.y = (u32)tmp[2] | ((u32)tmp[3] << 16);
    v.z = (u32)tmp[4] | ((u32)tmp[5] << 16);
    v.w = (u32)tmp[6] | ((u32)tmp[7] << 16);
    *(uint4*)(dst + q*8) = v;
  }
}

// ---------------------------------------------------------------- small prep: zero stat buckets + pack weights bf16
__global__ __launch_bounds__(256) void prep_small(const float* __restrict__ W0,
                                                  const float* __restrict__ W1,
                                                  const float* __restrict__ W2,
                                                  u16* __restrict__ W0bf,
                                                  u16* __restrict__ W1bf,
                                                  u16* __restrict__ W2bf,
                                                  float* __restrict__ statsF){
  const int blk = blockIdx.x, t = threadIdx.x;
  if (blk < 48){
#pragma unroll
    for (int k = 0; k < 4; k++) statsF[blk*1024 + k*256 + t] = 0.f;
  } else if (blk == 48){
    for (int i = t; i < 64*96; i += 256){
      int n = i / 96, k = i % 96;
      W0bf[i] = (k < 67) ? f2bf(W0[n*67 + k]) : (u16)0;
    }
  } else if (blk <= 50){
    for (int i = (blk-49)*256 + t; i < 128*64; i += 512) W1bf[i] = f2bf(W1[i]);
  } else if (blk <= 54){
    for (int i = (blk-51)*256 + t; i < 128*128; i += 1024) W2bf[i] = f2bf(W2[i]);
  }
}

// ---------------------------------------------------------------- layer 0: gather + matmul (K=96 padded), stats
__global__ __launch_bounds__(256) void l0_kernel(const u16* __restrict__ XP,
                                                 const int* __restrict__ gidx,
                                                 const u16* __restrict__ W0bf,
                                                 u16* __restrict__ y0,
                                                 float* __restrict__ bsum, float* __restrict__ bsqr){
  __shared__ float lsum[64], lsqr[64];
  const int blk = blockIdx.x, t = threadIdx.x;
  const int b = blk >> 8, j = blk & 255;
  const int wave = t >> 6, lane = t & 63, lrow = lane & 15, lq = lane >> 4;
  if (t < 64){ lsum[t] = 0.f; lsqr[t] = 0.f; }
  __syncthreads();
  const size_t srow = (size_t)blk * 128;
  const int m0 = wave*32 + lrow, m1 = m0 + 16;
  const int gbase = b*32768 + j*128;
  const int p0 = gidx[gbase + m0];
  const int p1 = gidx[gbase + m1];
  const bf16x8* ar0 = (const bf16x8*)(XP + ((size_t)b*NPTS + p0)*96);
  const bf16x8* ar1 = (const bf16x8*)(XP + ((size_t)b*NPTS + p1)*96);
  f32x4 acc[2][4];
#pragma unroll
  for (int mt = 0; mt < 2; mt++)
#pragma unroll
    for (int nt = 0; nt < 4; nt++){ f32x4 z = {0.f,0.f,0.f,0.f}; acc[mt][nt] = z; }
#pragma unroll
  for (int ks = 0; ks < 3; ks++){
    bf16x8 af0 = ar0[ks*4 + lq];
    bf16x8 af1 = ar1[ks*4 + lq];
#pragma unroll
    for (int nt = 0; nt < 4; nt++){
      bf16x8 bb = *(const bf16x8*)(W0bf + (nt*16 + lrow)*96 + ks*32 + lq*8);
      acc[0][nt] = __builtin_amdgcn_mfma_f32_16x16x32_bf16(af0, bb, acc[0][nt], 0, 0, 0);
      acc[1][nt] = __builtin_amdgcn_mfma_f32_16x16x32_bf16(af1, bb, acc[1][nt], 0, 0, 0);
    }
  }
#pragma unroll
  for (int nt = 0; nt < 4; nt++){
    float s = 0.f, s2 = 0.f;
#pragma unroll
    for (int mt = 0; mt < 2; mt++){
#pragma unroll
      for (int i = 0; i < 4; i++){
        float u = acc[mt][nt][i];
        s += u; s2 = fmaf(u, u, s2);
        int m = wave*32 + mt*16 + lq*4 + i;
        y0[(srow + m)*64 + nt*16 + lrow] = f2bf(u);
      }
    }
    s  += __shfl_xor(s, 16, 64);  s  += __shfl_xor(s, 32, 64);
    s2 += __shfl_xor(s2, 16, 64); s2 += __shfl_xor(s2, 32, 64);
    if (lane < 16){ atomicAdd(&lsum[nt*16 + lane], s); atomicAdd(&lsqr[nt*16 + lane], s2); }
  }
  __syncthreads();
  if (t < 64){
    int bkt = blk & 63;
    atomicAdd(&bsum[bkt*128 + t], lsum[t]);
    atomicAdd(&bsqr[bkt*128 + t], lsqr[t]);
  }
}

// ---------------------------------------------------------------- stats finalize: a = g*rsqrt(var+eps), d = be - mean*a
__global__ __launch_bounds__(128) void stats_kernel(const float* __restrict__ bsum,
                                                    const float* __restrict__ bsqr,
                                                    const float* __restrict__ g,
                                                    const float* __restrict__ be,
                                                    float* __restrict__ a, float* __restrict__ d, int C){
  const int c = threadIdx.x;
  if (c >= C) return;
  float s = 0.f, s2 = 0.f;
  for (int k = 0; k < 64; k++){ s += bsum[k*128 + c]; s2 += bsqr[k*128 + c]; }
  const float inv = 1.f / (float)STOT;
  float m = s * inv;
  float v = s2 * inv - m*m;
  float aa = g[c] / sqrtf(v + 1e-5f);
  a[c] = aa;
  d[c] = be[c] - m*aa;
}

__device__ __forceinline__ bf16x8 load_bn_relu(const u16* __restrict__ row, int ko,
                                               const float* __restrict__ av,
                                               const float* __restrict__ dv){
  uint4 r = *(const uint4*)(row + ko);
  u32 w[4] = {r.x, r.y, r.z, r.w};
  bf16x8 out;
#pragma unroll
  for (int jj = 0; jj < 8; jj++){
    u16 us = (u16)(w[jj >> 1] >> ((jj & 1) * 16));
    float h = fmaxf(fmaf(av[ko + jj], bf2f(us), dv[ko + jj]), 0.f);
    out[jj] = (short)f2bf(h);
  }
  return out;
}

// ---------------------------------------------------------------- layer 1: K=64 -> Cout=128
__global__ __launch_bounds__(256) void l1_kernel(const u16* __restrict__ y0,
                                                 const u16* __restrict__ W1bf,
                                                 const float* __restrict__ a0, const float* __restrict__ d0,
                                                 u16* __restrict__ y1,
                                                 float* __restrict__ bsum, float* __restrict__ bsqr){
  __shared__ float lsum[128], lsqr[128];
  __shared__ float av[64], dv[64];
  const int blk = blockIdx.x, t = threadIdx.x;
  const int wave = t >> 6, lane = t & 63, lrow = lane & 15, lq = lane >> 4;
  if (t < 128){ lsum[t] = 0.f; lsqr[t] = 0.f; }
  if (t < 64){ av[t] = a0[t]; dv[t] = d0[t]; }
  __syncthreads();
  const size_t srow = (size_t)blk * 128;
  const int m0 = wave*32 + lrow, m1 = m0 + 16;
  const u16* row0 = y0 + (srow + m0)*64;
  const u16* row1 = y0 + (srow + m1)*64;
  f32x4 acc[2][8];
#pragma unroll
  for (int mt = 0; mt < 2; mt++)
#pragma unroll
    for (int nt = 0; nt < 8; nt++){ f32x4 z = {0.f,0.f,0.f,0.f}; acc[mt][nt] = z; }
#pragma unroll
  for (int ks = 0; ks < 2; ks++){
    const int ko = ks*32 + lq*8;
    bf16x8 af0 = load_bn_relu(row0, ko, av, dv);
    bf16x8 af1 = load_bn_relu(row1, ko, av, dv);
#pragma unroll
    for (int nt = 0; nt < 8; nt++){
      bf16x8 bb = *(const bf16x8*)(W1bf + (nt*16 + lrow)*64 + ko);
      acc[0][nt] = __builtin_amdgcn_mfma_f32_16x16x32_bf16(af0, bb, acc[0][nt], 0, 0, 0);
      acc[1][nt] = __builtin_amdgcn_mfma_f32_16x16x32_bf16(af1, bb, acc[1][nt], 0, 0, 0);
    }
  }
#pragma unroll
  for (int nt = 0; nt < 8; nt++){
    float s = 0.f, s2 = 0.f;
#pragma unroll
    for (int mt = 0; mt < 2; mt++){
#pragma unroll
      for (int i = 0; i < 4; i++){
        float u = acc[mt][nt][i];
        s += u; s2 = fmaf(u, u, s2);
        int m = wave*32 + mt*16 + lq*4 + i;
        y1[(srow + m)*128 + nt*16 + lrow] = f2bf(u);
      }
    }
    s  += __shfl_xor(s, 16, 64);  s  += __shfl_xor(s, 32, 64);
    s2 += __shfl_xor(s2, 16, 64); s2 += __shfl_xor(s2, 32, 64);
    if (lane < 16){ atomicAdd(&lsum[nt*16 + lane], s); atomicAdd(&lsqr[nt*16 + lane], s2); }
  }
  __syncthreads();
  if (t < 128){
    int bkt = blk & 63;
    atomicAdd(&bsum[bkt*128 + t], lsum[t]);
    atomicAdd(&bsqr[bkt*128 + t], lsqr[t]);
  }
}

// ---------------------------------------------------------------- layer 2: K=128 -> Cout=128; emit per-group max/min of pre-BN y2
__global__ __launch_bounds__(256) void l2_kernel(const u16* __restrict__ y1,
                                                 const u16* __restrict__ W2bf,
                                                 const float* __restrict__ a1, const float* __restrict__ d1,
                                                 float* __restrict__ maxb, float* __restrict__ minb,
                                                 float* __restrict__ bsum, float* __restrict__ bsqr){
  __shared__ float lsum[128], lsqr[128];
  __shared__ float av[128], dv[128];
  const int blk = blockIdx.x, t = threadIdx.x;
  const int wave = t >> 6, lane = t & 63, lrow = lane & 15, lq = lane >> 4;
  if (t < 128){ lsum[t] = 0.f; lsqr[t] = 0.f; av[t] = a1[t]; dv[t] = d1[t]; }
  __syncthreads();
  const size_t srow = (size_t)blk * 128;
  const int m0 = wave*32 + lrow, m1 = m0 + 16;
  const u16* row0 = y1 + (srow + m0)*128;
  const u16* row1 = y1 + (srow + m1)*128;
  f32x4 acc[2][8];
#pragma unroll
  for (int mt = 0; mt < 2; mt++)
#pragma unroll
    for (int nt = 0; nt < 8; nt++){ f32x4 z = {0.f,0.f,0.f,0.f}; acc[mt][nt] = z; }
#pragma unroll
  for (int ks = 0; ks < 4; ks++){
    const int ko = ks*32 + lq*8;
    bf16x8 af0 = load_bn_relu(row0, ko, av, dv);
    bf16x8 af1 = load_bn_relu(row1, ko, av, dv);
#pragma unroll
    for (int nt = 0; nt < 8; nt++){
      bf16x8 bb = *(const bf16x8*)(W2bf + (nt*16 + lrow)*128 + ko);
      acc[0][nt] = __builtin_amdgcn_mfma_f32_16x16x32_bf16(af0, bb, acc[0][nt], 0, 0, 0);
      acc[1][nt] = __builtin_amdgcn_mfma_f32_16x16x32_bf16(af1, bb, acc[1][nt], 0, 0, 0);
    }
  }
#pragma unroll
  for (int nt = 0; nt < 8; nt++){
    float s = 0.f, s2 = 0.f, mx = -3.4e38f, mn = 3.4e38f;
#pragma unroll
    for (int mt = 0; mt < 2; mt++){
#pragma unroll
      for (int i = 0; i < 4; i++){
        float u = acc[mt][nt][i];
        s += u; s2 = fmaf(u, u, s2);
        mx = fmaxf(mx, u); mn = fminf(mn, u);
      }
    }
    s  += __shfl_xor(s, 16, 64);  s  += __shfl_xor(s, 32, 64);
    s2 += __shfl_xor(s2, 16, 64); s2 += __shfl_xor(s2, 32, 64);
    mx = fmaxf(mx, __shfl_xor(mx, 16, 64)); mx = fmaxf(mx, __shfl_xor(mx, 32, 64));
    mn = fminf(mn, __shfl_xor(mn, 16, 64)); mn = fminf(mn, __shfl_xor(mn, 32, 64));
    if (lane < 16){
      size_t gi = ((size_t)blk*4 + wave)*128 + nt*16 + lane;
      maxb[gi] = mx; minb[gi] = mn;
      atomicAdd(&lsum[nt*16 + lane], s); atomicAdd(&lsqr[nt*16 + lane], s2);
    }
  }
  __syncthreads();
  if (t < 128){
    int bkt = blk & 63;
    atomicAdd(&bsum[bkt*128 + t], lsum[t]);
    atomicAdd(&bsqr[bkt*128 + t], lsqr[t]);
  }
}

// ---------------------------------------------------------------- final: BN2+relu on group max/min, transpose-store [B,128,NP]
__global__ __launch_bounds__(256) void final_kernel(const float* __restrict__ maxb,
                                                    const float* __restrict__ minb,
                                                    const float* __restrict__ a2, const float* __restrict__ d2,
                                                    float* __restrict__ out1){
  __shared__ float ldsb[64*129];
  __shared__ float av[128], dv[128];
  const int blk = blockIdx.x, t = threadIdx.x;
  const int b = blk >> 4, np0 = (blk & 15) << 6;
  if (t < 128){ av[t] = a2[t]; dv[t] = d2[t]; }
  __syncthreads();
  const size_t base = ((size_t)b*NPOINT + np0)*128;
  for (int itc = 0; itc < 32; itc++){
    int e = t + (itc << 8);
    int npl = e >> 7, c = e & 127;
    float a = av[c];
    float mxv = maxb[base + e], mnv = minb[base + e];
    float vsel = (a >= 0.f) ? mxv : mnv;
    ldsb[npl*129 + c] = fmaxf(fmaf(a, vsel, dv[c]), 0.f);
  }
  __syncthreads();
  for (int itc = 0; itc < 32; itc++){
    int e = t + (itc << 8);
    int c = e >> 6, npl = e & 63;
    out1[((size_t)b*128 + c)*NPOINT + np0 + npl] = ldsb[npl*129 + c];
  }
}

// ---------------------------------------------------------------- launch
extern "C" void kernel_launch(void* const* d_in, const int* in_sizes, int n_in,
                              void* d_out, int out_size, void* d_ws, size_t ws_size,
                              hipStream_t stream) {
  const float* xyz    = (const float*)d_in[0];
  const float* points = (const float*)d_in[1];
  const int*   finit  = (const int*)d_in[2];
  const int*   gidx   = (const int*)d_in[3];
  const float* W0  = (const float*)d_in[4];
  const float* g0v = (const float*)d_in[6];
  const float* be0 = (const float*)d_in[7];
  const float* W1  = (const float*)d_in[8];
  const float* g1v = (const float*)d_in[10];
  const float* be1 = (const float*)d_in[11];
  const float* W2  = (const float*)d_in[12];
  const float* g2v = (const float*)d_in[14];
  const float* be2 = (const float*)d_in[15];

  float* out0 = (float*)d_out;
  float* out1 = out0 + 16*3*NPOINT;   // 49152

  char* ws = (char*)d_ws;
  u16* XP = (u16*)ws;                               // 48 MiB, dead after l0
  u16* y1 = (u16*)ws;                               // 128 MiB (aliases XP; written in l1)
  u16* y0 = (u16*)(ws + 134217728);                 // 64 MiB
  float4* xpk = (float4*)(ws + 134217728);          // 4 MiB, used ONLY by fps (runs first; stream-ordered)
  float* maxb = (float*)(ws + 134217728);           // aliases y0 (dead after l1)
  float* minb = (float*)(ws + 134217728 + 8388608);
  float* statsF = (float*)(ws + 201326592);
  float* bsum0 = statsF;          float* bsqr0 = statsF + 8192;
  float* bsum1 = statsF + 16384;  float* bsqr1 = statsF + 24576;
  float* bsum2 = statsF + 32768;  float* bsqr2 = statsF + 40960;
  float* a0 = statsF + 49152;       float* d0 = a0 + 128;
  float* a1 = statsF + 49152 + 256; float* d1 = a1 + 128;
  float* a2 = statsF + 49152 + 512; float* d2 = a2 + 128;
  u16* W0bf = (u16*)(statsF + 49920);
  u16* W1bf = W0bf + 64*96;
  u16* W2bf = W1bf + 128*64;

  fps_kernel<<<16, 1024, 0, stream>>>(xyz, finit, xpk, out0);
  prep_small<<<64, 256, 0, stream>>>(W0, W1, W2, W0bf, W1bf, W2bf, statsF);
  pack_kernel<<<1024, 256, 0, stream>>>(xyz, points, XP);
  l0_kernel<<<4096, 256, 0, stream>>>(XP, gidx, W0bf, y0, bsum0, bsqr0);
  stats_kernel<<<1, 128, 0, stream>>>(bsum0, bsqr0, g0v, be0, a0, d0, 64);
  l1_kernel<<<4096, 256, 0, stream>>>(y0, W1bf, a0, d0, y1, bsum1, bsqr1);
  stats_kernel<<<1, 128, 0, stream>>>(bsum1, bsqr1, g1v, be1, a1, d1, 128);
  l2_kernel<<<4096, 256, 0, stream>>>(y1, W2bf, a1, d1, maxb, minb, bsum2, bsqr2);
  stats_kernel<<<1, 128, 0, stream>>>(bsum2, bsqr2, g2v, be2, a2, d2, 128);
  final_kernel<<<256, 256, 0, stream>>>(maxb, minb, a2, d2, out1);
}